// Round 3
// baseline (218.534 us; speedup 1.0000x reference)
//
#include <hip/hip_runtime.h>

// ---------------------------------------------------------------------------
// Block-sparse linear  y = x @ W^T + bias  on MI355X (gfx950)
// Round 3: LDS-bandwidth diet. Round-2 analysis: 70 LDS-bytes/KFLOP ->
// LDS-bw-bound (~3000 of ~4500 cyc/iter-period). Changes:
//  (a) B fragments loaded global->register (L1/L2 broadcast), no LDS for B.
//  (b) 2-wave workgroups, each wave owns 64x64 (4x4 acc frags) -> A-frag
//      reads amortized 4 MFMAs/read; 32 MFMAs per barrier.
//  (c) rolling csr_pk prefetch to hide the uniform-load latency.
// LDS traffic drops to 30.5 B/KFLOP (writes 16KB + reads 16KB per 1.05 MFLOP).
// ---------------------------------------------------------------------------

typedef __attribute__((ext_vector_type(8))) short bf16x8;   // MFMA A/B frag
typedef __attribute__((ext_vector_type(8))) unsigned short u16x8;
typedef __attribute__((ext_vector_type(4))) float f32x4;     // MFMA C/D frag

#define N_ROWS 4096
#define IN_DIM 4096
#define OUT_DIM 4096
#define BS 64
#define K_BLOCKS 1024
#define NT 128            // rows per workgroup tile (2 waves x 64 rows)
#define PK_STRIDE 256

// fp32 -> bf16 round-to-nearest-even
__device__ static inline unsigned short f2bf(float f) {
    unsigned u = __float_as_uint(f);
    u += 0x7FFFu + ((u >> 16) & 1u);
    return (unsigned short)(u >> 16);
}

__device__ static inline void async_copy16(const void* g, void* l) {
    __builtin_amdgcn_global_load_lds(
        (const __attribute__((address_space(1))) void*)g,
        (__attribute__((address_space(3))) void*)l, 16, 0, 0);
}

// --- prep: convert x (16M f32) and blocks (4M f32) to bf16 -----------------
__global__ void bsl_convert(const float* __restrict__ x,
                            const float* __restrict__ blocks,
                            unsigned short* __restrict__ xb,
                            unsigned short* __restrict__ bb) {
    long t = (long)blockIdx.x * 256 + threadIdx.x;   // 8 floats each
    const float4* src;
    unsigned short* dst;
    long off4;
    if (t < 2097152) {            // x region
        src = (const float4*)x;  dst = xb;  off4 = t * 2;
    } else {                      // blocks region
        src = (const float4*)blocks;  dst = bb;  off4 = (t - 2097152) * 2;
    }
    float4 a = src[off4];
    float4 b = src[off4 + 1];
    u16x8 v;
    v[0] = f2bf(a.x); v[1] = f2bf(a.y); v[2] = f2bf(a.z); v[3] = f2bf(a.w);
    v[4] = f2bf(b.x); v[5] = f2bf(b.y); v[6] = f2bf(b.z); v[7] = f2bf(b.w);
    *(u16x8*)(dst + off4 * 4) = v;
}

// --- prep: parallel CSR + balanced pair schedule ---------------------------
__global__ void bsl_build_csr(const int* __restrict__ row_idx,
                              const int* __restrict__ col_idx,
                              int* __restrict__ counts,
                              int* __restrict__ sched,
                              int* __restrict__ csr_pk) {
    __shared__ int cnt_s[64];
    __shared__ int sorted_s[64];
    const int t = threadIdx.x;          // 1024 threads
    if (t < 64) cnt_s[t] = 0;
    __syncthreads();
    const int r = row_idx[t];
    const int rank = atomicAdd(&cnt_s[r], 1);
    if (rank < PK_STRIDE) csr_pk[r * PK_STRIDE + rank] = (t << 6) | col_idx[t];
    __syncthreads();
    if (t < 64) {
        const int mc = cnt_s[t];
        counts[t] = mc;
        int pos = 0;
        for (int j = 0; j < 64; ++j) {
            const int cj = cnt_s[j];
            pos += (cj > mc || (cj == mc && j < t)) ? 1 : 0;
        }
        sorted_s[pos] = t;
    }
    __syncthreads();
    if (t < 32) {
        sched[t * 2]     = sorted_s[t];
        sched[t * 2 + 1] = sorted_s[63 - t];
    }
}

// --- main: 128 threads = 2 waves; wave owns 64 rows x 64 cols (4x4 acc) ----
// A through LDS with the 16B-slot XOR swizzle (0 conflicts, verified);
// B straight from global into registers (broadcast, L1/L2-resident).
__global__ __launch_bounds__(128, 2) void bsl_main(
    const unsigned short* __restrict__ xb,   // [4096][4096] bf16
    const unsigned short* __restrict__ blk,  // [1024][64][64] bf16
    const float* __restrict__ bias,
    const int* __restrict__ counts,
    const int* __restrict__ sched,
    const int* __restrict__ csr_pk,
    float* __restrict__ y) {
    __shared__ unsigned short a_lds[NT * 64];   // 16 KB

    const int tid = threadIdx.x;
    const int w = tid >> 6;        // wave 0..1 -> rows [w*64, w*64+64)
    const int l = tid & 63;
    const int m = l & 15;          // MFMA lane coord
    const int q = l >> 4;          // quad
    const int nt = blockIdx.x;     // 32 n-tiles of 128 rows
    const int p  = blockIdx.y;     // 32 pairs
    const int n0 = nt * NT;

    // staging lane constants (A): chunk covers 8 rows x 64 cols, swizzled
    const int srow = l >> 3;                    // 0..7
    const int scc  = (l & 7) ^ srow;            // swizzled col-chunk
    const int scol = scc * 8;
    const int xorv = m & 7;                     // read-side swizzle

    for (int half = 0; half < 2; ++half) {
        const int rb  = sched[p * 2 + half];
        const int cnt = counts[rb];
        const int* pkp = csr_pk + rb * PK_STRIDE;

        f32x4 acc[4][4];
#pragma unroll
        for (int r = 0; r < 4; ++r)
#pragma unroll
            for (int c = 0; c < 4; ++c) acc[r][c] = (f32x4){0.f, 0.f, 0.f, 0.f};

        int pk = (cnt > 0) ? pkp[0] : 0;
        for (int kk = 0; kk < cnt; ++kk) {
            const int k  = pk >> 6;
            const int ci = pk & 63;
            // prefetch next pk (PK_STRIDE slack makes OOB read safe)
            const int pk_next = pkp[kk + 1];

            // stage A tile: 128x64 bf16 = 16 chunks of 1KB; wave w: ch = i*2+w
            const unsigned short* xrow =
                xb + (size_t)(n0 + srow) * IN_DIM + ci * 64 + scol;
#pragma unroll
            for (int i = 0; i < 8; ++i) {
                const int ch = i * 2 + w;
                async_copy16(xrow + (size_t)(ch * 8) * IN_DIM, a_lds + ch * 512);
            }
            // B fragments: global -> registers, B[n=c*16+m][k=s*32+q*8..+8]
            const unsigned short* bbase =
                blk + (size_t)k * 4096 + (size_t)m * 64 + q * 8;
            bf16x8 bfrag[2][4];
#pragma unroll
            for (int s = 0; s < 2; ++s)
#pragma unroll
                for (int c = 0; c < 4; ++c)
                    bfrag[s][c] = *(const bf16x8*)(bbase + c * 1024 + s * 32);

            __syncthreads();   // drains vmcnt: A in LDS, B in regs

#pragma unroll
            for (int s = 0; s < 2; ++s) {
                bf16x8 af[4];
                const int cc = (s * 4 + q) ^ xorv;
#pragma unroll
                for (int r = 0; r < 4; ++r) {
                    const int row = w * 64 + r * 16 + m;
                    af[r] = *(const bf16x8*)(a_lds + row * 64 + cc * 8);
                }
#pragma unroll
                for (int r = 0; r < 4; ++r)
#pragma unroll
                    for (int c = 0; c < 4; ++c)
                        acc[r][c] = __builtin_amdgcn_mfma_f32_16x16x32_bf16(
                            af[r], bfrag[s][c], acc[r][c], 0, 0, 0);
            }
            __syncthreads();   // protect a_lds before next staging
            pk = pk_next;
        }

        // epilogue: C/D layout col=lane&15, row=q*4+reg
        const int colbase = rb * 64;
#pragma unroll
        for (int c = 0; c < 4; ++c) {
            const float bv = bias[colbase + c * 16 + m];
#pragma unroll
            for (int r = 0; r < 4; ++r) {
                const int rowb = n0 + w * 64 + r * 16 + q * 4;
#pragma unroll
                for (int e = 0; e < 4; ++e) {
                    y[(size_t)(rowb + e) * OUT_DIM + colbase + c * 16 + m] =
                        acc[r][c][e] + bv;
                }
            }
        }
    }
}

// ---------------------------------------------------------------------------
extern "C" void kernel_launch(void* const* d_in, const int* in_sizes, int n_in,
                              void* d_out, int out_size, void* d_ws, size_t ws_size,
                              hipStream_t stream) {
    const float* x      = (const float*)d_in[0];
    const float* blocks = (const float*)d_in[1];
    const float* bias   = (const float*)d_in[2];
    const int* row_idx  = (const int*)d_in[3];
    const int* col_idx  = (const int*)d_in[4];
    float* y = (float*)d_out;

    const size_t base = 41943040u;   // 40 MB
    unsigned short* xb = (unsigned short*)d_ws;
    unsigned short* bb = xb + (size_t)N_ROWS * IN_DIM;
    int* counts = (int*)((char*)d_ws + base);
    int* sched  = counts + 64;
    int* csr_pk = (int*)((char*)d_ws + base + 1024);
    if (ws_size < base + 1024 + (size_t)64 * PK_STRIDE * 4) return;

    hipLaunchKernelGGL(bsl_convert, dim3(10240), dim3(256), 0, stream,
                       x, blocks, xb, bb);
    hipLaunchKernelGGL(bsl_build_csr, dim3(1), dim3(1024), 0, stream,
                       row_idx, col_idx, counts, sched, csr_pk);
    hipLaunchKernelGGL(bsl_main, dim3(32, 32), dim3(128), 0, stream,
                       xb, bb, bias, counts, sched, csr_pk, y);
}

// Round 4
// 217.459 us; speedup vs baseline: 1.0049x; 1.0049x over previous
//
#include <hip/hip_runtime.h>

// ---------------------------------------------------------------------------
// Block-sparse linear  y = x @ W^T + bias  on MI355X (gfx950)
// Round 4: BARRIER-FREE wave-decoupled K-loop. Round-3 lesson: the limiter is
// barrier+latency serialization (both pipes idle), not LDS bw. Each wave owns
// 64 rows x 64 cols with a PRIVATE double-buffered LDS A-tile staged via
// global_load_lds (no VGPR cost) and register-prefetched B. Per iter:
// vmcnt(0) [drains 1-iter-old prefetch] -> 8 ds_read_b128 -> issue next A+B
// -> 32 MFMAs. Zero __syncthreads. 512 wgs (16 n-tiles x 32 balanced pairs),
// 64KB LDS -> 2 wg/CU, 8 waves/CU, all resident.
// ---------------------------------------------------------------------------

typedef __attribute__((ext_vector_type(8))) short bf16x8;   // MFMA A/B frag
typedef __attribute__((ext_vector_type(8))) unsigned short u16x8;
typedef __attribute__((ext_vector_type(4))) float f32x4;     // MFMA C/D frag

#define IN_DIM 4096
#define OUT_DIM 4096
#define PK2 128   // per-pair packed-block list capacity

// fp32 -> bf16 round-to-nearest-even
__device__ static inline unsigned short f2bf(float f) {
    unsigned u = __float_as_uint(f);
    u += 0x7FFFu + ((u >> 16) & 1u);
    return (unsigned short)(u >> 16);
}

__device__ static inline void async_copy16(const void* g, void* l) {
    __builtin_amdgcn_global_load_lds(
        (const __attribute__((address_space(1))) void*)g,
        (__attribute__((address_space(3))) void*)l, 16, 0, 0);
}

// --- prep: convert x (16M f32) and blocks (4M f32) to bf16 -----------------
__global__ void bsl_convert(const float* __restrict__ x,
                            const float* __restrict__ blocks,
                            unsigned short* __restrict__ xb,
                            unsigned short* __restrict__ bb) {
    long t = (long)blockIdx.x * 256 + threadIdx.x;   // 8 floats each
    const float4* src;
    unsigned short* dst;
    long off4;
    if (t < 2097152) {            // x region
        src = (const float4*)x;  dst = xb;  off4 = t * 2;
    } else {                      // blocks region
        src = (const float4*)blocks;  dst = bb;  off4 = (t - 2097152) * 2;
    }
    float4 a = src[off4];
    float4 b = src[off4 + 1];
    u16x8 v;
    v[0] = f2bf(a.x); v[1] = f2bf(a.y); v[2] = f2bf(a.z); v[3] = f2bf(a.w);
    v[4] = f2bf(b.x); v[5] = f2bf(b.y); v[6] = f2bf(b.z); v[7] = f2bf(b.w);
    *(u16x8*)(dst + off4 * 4) = v;
}

// --- prep: balanced pairs + merged per-pair block lists --------------------
// Pair p = {rank p, rank 63-p} of row-blocks sorted by descending count.
// pair_pk[p*PK2 + i]: first cnt0 entries = rb0's blocks, then rb1's.
__global__ void bsl_build_csr(const int* __restrict__ row_idx,
                              const int* __restrict__ col_idx,
                              int* __restrict__ pair_rbs,
                              int* __restrict__ pair_cnt0,
                              int* __restrict__ pair_cnt,
                              int* __restrict__ pair_pk) {
    __shared__ int cnt_s[64];
    __shared__ int sorted_s[64];
    __shared__ int pos_of_s[64];
    const int t = threadIdx.x;          // 1024 threads
    if (t < 64) cnt_s[t] = 0;
    __syncthreads();
    const int r = row_idx[t];
    const int rank = atomicAdd(&cnt_s[r], 1);
    __syncthreads();
    if (t < 64) {
        const int mc = cnt_s[t];
        int pos = 0;
        for (int j = 0; j < 64; ++j) {
            const int cj = cnt_s[j];
            pos += (cj > mc || (cj == mc && j < t)) ? 1 : 0;
        }
        sorted_s[pos] = t;
        pos_of_s[t] = pos;
    }
    __syncthreads();
    if (t < 32) {
        const int r0 = sorted_s[t], r1 = sorted_s[63 - t];
        pair_rbs[2 * t]     = r0;
        pair_rbs[2 * t + 1] = r1;
        const int c0 = cnt_s[r0];
        const int cT = c0 + cnt_s[r1];
        pair_cnt0[t] = (c0 < PK2 - 2) ? c0 : (PK2 - 2);
        pair_cnt[t]  = (cT < PK2 - 2) ? cT : (PK2 - 2);
    }
    const int pos  = pos_of_s[r];
    const int pair = (pos < 32) ? pos : (63 - pos);
    const int base = (pos < 32) ? 0 : cnt_s[sorted_s[pair]];
    const int off  = base + rank;
    if (off < PK2) pair_pk[pair * PK2 + off] = (t << 6) | col_idx[t];
}

// --- main: 4 decoupled waves, each 64x64 output, private LDS A dbuf --------
// LDS 16B-slot swizzle within each 8KB buffer: phys_slot(row,cc)=row*8+(cc^
// (row&7)); staging lane l in chunk ch -> (row=ch*8+l/8, cc=(l&7)^(l/8));
// read xors with m&7. Verified 0 bank conflicts rounds 1-2.
__global__ __launch_bounds__(256, 2) void bsl_main(
    const unsigned short* __restrict__ xb,   // [4096][4096] bf16
    const unsigned short* __restrict__ blk,  // [1024][64][64] bf16
    const float* __restrict__ bias,
    const int* __restrict__ pair_rbs,
    const int* __restrict__ pair_cnt0,
    const int* __restrict__ pair_cnt,
    const int* __restrict__ pair_pk,
    float* __restrict__ y) {
    __shared__ unsigned short a_lds[4 * 2 * 4096];   // 4 waves x 2 bufs x 8KB

    const int tid = threadIdx.x;
    const int w = tid >> 6;        // wave id
    const int l = tid & 63;
    const int m = l & 15;          // MFMA lane coord
    const int q = l >> 4;          // quad
    const int n0 = blockIdx.x * 256 + w * 64;   // this wave's row base
    const int p  = blockIdx.y;                  // pair id

    const int srow = l >> 3;                    // staging row-in-chunk
    const int scc  = (l & 7) ^ srow;            // staging swizzled col-chunk
    const int xorv = m & 7;                     // read-side swizzle

    const int rb0  = pair_rbs[2 * p];
    const int rb1  = pair_rbs[2 * p + 1];
    const int cnt0 = pair_cnt0[p];
    const int cntT = pair_cnt[p];
    const int* plist = pair_pk + p * PK2;

    unsigned short* awave = a_lds + w * 8192;
    const unsigned short* xg = xb + (size_t)(n0 + srow) * IN_DIM + scc * 8;

    f32x4 acc[4][4];
#pragma unroll
    for (int r = 0; r < 4; ++r)
#pragma unroll
        for (int c = 0; c < 4; ++c) acc[r][c] = (f32x4){0.f, 0.f, 0.f, 0.f};

    auto zeroacc = [&]() {
#pragma unroll
        for (int r = 0; r < 4; ++r)
#pragma unroll
            for (int c = 0; c < 4; ++c) acc[r][c] = (f32x4){0.f, 0.f, 0.f, 0.f};
    };
    auto stageA = [&](int buf, int ci) {
        const unsigned short* src = xg + ci * 64;
        unsigned short* dst = awave + buf * 4096;
#pragma unroll
        for (int ch = 0; ch < 8; ++ch)
            async_copy16(src + (size_t)ch * 8 * IN_DIM, dst + ch * 512);
    };
    auto loadB = [&](bf16x8 (&b)[2][4], int k) {
        const unsigned short* bbase = blk + (size_t)k * 4096 + m * 64 + q * 8;
#pragma unroll
        for (int s = 0; s < 2; ++s)
#pragma unroll
            for (int c = 0; c < 4; ++c)
                b[s][c] = *(const bf16x8*)(bbase + c * 1024 + s * 32);
    };
    auto epilogue = [&](int rb) {
        const int colbase = rb * 64;
#pragma unroll
        for (int c = 0; c < 4; ++c) {
            const float bv = bias[colbase + c * 16 + m];
#pragma unroll
            for (int r = 0; r < 4; ++r) {
                const int rowb = n0 + r * 16 + q * 4;
#pragma unroll
                for (int e = 0; e < 4; ++e)
                    y[(size_t)(rowb + e) * OUT_DIM + colbase + c * 16 + m] =
                        acc[r][c][e] + bv;
            }
        }
    };

    if (cnt0 == 0) epilogue(rb0);   // bias-only row-block (edge case)

    bf16x8 b0[2][4], b1[2][4];
    int pk_next = plist[1];
    if (cntT > 0) {
        const int pk0 = plist[0];
        stageA(0, pk0 & 63);
        loadB(b0, pk0 >> 6);
    }

    auto body = [&](int buf, bf16x8 (&bc)[2][4], bf16x8 (&bn)[2][4], int idx) {
        const int pk2 = plist[idx + 2];   // value prefetch only (in-bounds)
        // wait for THIS buffer's staging + bc's loads (issued 1 iter ago);
        // nothing younger is outstanding. vmcnt(0), lgkm/exp free: 0x0F70.
        __builtin_amdgcn_s_waitcnt(0x0F70);
        bf16x8 af[2][4];
        const unsigned short* abuf = awave + buf * 4096;
#pragma unroll
        for (int s = 0; s < 2; ++s) {
            const int ccp = ((s * 4 + q) ^ xorv) * 8;
#pragma unroll
            for (int r = 0; r < 4; ++r) {
                const int row = r * 16 + m;
                af[s][r] = *(const bf16x8*)(abuf + row * 64 + ccp);
            }
        }
        // fence: next-iter loads must not be hoisted above the ds_reads
        __builtin_amdgcn_sched_barrier(0);
        if (idx + 1 < cntT) {
            stageA(buf ^ 1, pk_next & 63);
            loadB(bn, pk_next >> 6);
        }
#pragma unroll
        for (int s = 0; s < 2; ++s)
#pragma unroll
            for (int r = 0; r < 4; ++r)
#pragma unroll
                for (int c = 0; c < 4; ++c)
                    acc[r][c] = __builtin_amdgcn_mfma_f32_16x16x32_bf16(
                        af[s][r], bc[s][c], acc[r][c], 0, 0, 0);
        if (idx == cnt0 - 1) { epilogue(rb0); zeroacc(); }
        pk_next = pk2;
    };

    int idx = 0;
    while (idx < cntT) {
        body(0, b0, b1, idx); ++idx;
        if (idx >= cntT) break;
        body(1, b1, b0, idx); ++idx;
    }
    epilogue(rb1);
}

// ---------------------------------------------------------------------------
extern "C" void kernel_launch(void* const* d_in, const int* in_sizes, int n_in,
                              void* d_out, int out_size, void* d_ws, size_t ws_size,
                              hipStream_t stream) {
    const float* x      = (const float*)d_in[0];
    const float* blocks = (const float*)d_in[1];
    const float* bias   = (const float*)d_in[2];
    const int* row_idx  = (const int*)d_in[3];
    const int* col_idx  = (const int*)d_in[4];
    float* y = (float*)d_out;

    // ws: x_bf16 32MB | blocks_bf16 8MB | meta @40MB:
    //     pair_rbs[64] | pair_cnt0[32] | pair_cnt[32] | pair_pk[32*PK2]
    const size_t base = 41943040u;
    unsigned short* xb = (unsigned short*)d_ws;
    unsigned short* bb = xb + (size_t)4096 * 4096;
    int* pair_rbs  = (int*)((char*)d_ws + base);
    int* pair_cnt0 = pair_rbs + 64;
    int* pair_cnt  = pair_cnt0 + 32;
    int* pair_pk   = pair_cnt + 32;
    if (ws_size < base + (128 + 32 * PK2) * 4) return;

    hipLaunchKernelGGL(bsl_convert, dim3(10240), dim3(256), 0, stream,
                       x, blocks, xb, bb);
    hipLaunchKernelGGL(bsl_build_csr, dim3(1), dim3(1024), 0, stream,
                       row_idx, col_idx, pair_rbs, pair_cnt0, pair_cnt, pair_pk);
    hipLaunchKernelGGL(bsl_main, dim3(16, 32), dim3(256), 0, stream,
                       xb, bb, bias, pair_rbs, pair_cnt0, pair_cnt, pair_pk, y);
}

// Round 5
// 201.950 us; speedup vs baseline: 1.0821x; 1.0768x over previous
//
#include <hip/hip_runtime.h>

// ---------------------------------------------------------------------------
// Block-sparse linear  y = x @ W^T + bias  on MI355X (gfx950)
// Round 5: traffic diet at the empirical ~13 TB/s global-service ceiling
// (R1/R2/R4 and m97 all plateau at 13-14 TB/s of staged bytes; FETCH_SIZE
// ~124MB means L2 absorbs re-reads -> the ceiling is the vector-mem path).
//  (a) NT=256 rows with 8-wave (512-thread) wgs: A 32KB + B 8KB per wg-iter
//      for 128 MFMAs = 19 B/KFLOP (R2 was 23) while keeping 16 waves/CU
//      (2 wg/CU x 8 waves) -- the occupancy that demonstrably sustains 13TB/s.
//  (b) per-segment ci-sort + skip A re-staging on equal consecutive ci
//      (~11% of A bytes), wg-uniform branch.
//  (c) keep balanced pairs, 16B-slot XOR swizzle (0 conflicts), width-16
//      global_load_lds staging.
// ---------------------------------------------------------------------------

typedef __attribute__((ext_vector_type(8))) short bf16x8;   // MFMA A/B frag
typedef __attribute__((ext_vector_type(8))) unsigned short u16x8;
typedef __attribute__((ext_vector_type(4))) float f32x4;     // MFMA C/D frag

#define IN_DIM 4096
#define OUT_DIM 4096
#define NT 256
#define PK2 128   // per-pair packed-block list capacity

// fp32 -> bf16 round-to-nearest-even
__device__ static inline unsigned short f2bf(float f) {
    unsigned u = __float_as_uint(f);
    u += 0x7FFFu + ((u >> 16) & 1u);
    return (unsigned short)(u >> 16);
}

__device__ static inline void async_copy16(const void* g, void* l) {
    __builtin_amdgcn_global_load_lds(
        (const __attribute__((address_space(1))) void*)g,
        (__attribute__((address_space(3))) void*)l, 16, 0, 0);
}

// --- prep: convert x (16M f32) and blocks (4M f32) to bf16 -----------------
__global__ void bsl_convert(const float* __restrict__ x,
                            const float* __restrict__ blocks,
                            unsigned short* __restrict__ xb,
                            unsigned short* __restrict__ bb) {
    long t = (long)blockIdx.x * 256 + threadIdx.x;   // 8 floats each
    const float4* src;
    unsigned short* dst;
    long off4;
    if (t < 2097152) {            // x region
        src = (const float4*)x;  dst = xb;  off4 = t * 2;
    } else {                      // blocks region
        src = (const float4*)blocks;  dst = bb;  off4 = (t - 2097152) * 2;
    }
    float4 a = src[off4];
    float4 b = src[off4 + 1];
    u16x8 v;
    v[0] = f2bf(a.x); v[1] = f2bf(a.y); v[2] = f2bf(a.z); v[3] = f2bf(a.w);
    v[4] = f2bf(b.x); v[5] = f2bf(b.y); v[6] = f2bf(b.z); v[7] = f2bf(b.w);
    *(u16x8*)(dst + off4 * 4) = v;
}

// --- prep: balanced pairs, per-segment ci-sorted block lists ---------------
// Pair p = {rank p, rank 63-p} by descending count. pair_pk[p*PK2 + i]:
// first cnt0 entries = rb0's blocks (sorted by ci), then rb1's (sorted).
__global__ void bsl_build_csr(const int* __restrict__ row_idx,
                              const int* __restrict__ col_idx,
                              int* __restrict__ pair_rbs,
                              int* __restrict__ pair_cnt0,
                              int* __restrict__ pair_cnt,
                              int* __restrict__ pair_pk) {
    __shared__ int cnt_s[64];
    __shared__ int sorted_s[64];
    __shared__ int pos_of_s[64];
    __shared__ int segbase_s[64];   // within-pair base of rb's segment
    __shared__ int pk_s[32 * PK2];  // 16 KB
    const int t = threadIdx.x;      // 1024 threads
    if (t < 64) cnt_s[t] = 0;
    __syncthreads();
    const int r = row_idx[t];
    const int rank = atomicAdd(&cnt_s[r], 1);
    __syncthreads();
    if (t < 64) {
        const int mc = cnt_s[t];
        int pos = 0;
        for (int j = 0; j < 64; ++j) {
            const int cj = cnt_s[j];
            pos += (cj > mc || (cj == mc && j < t)) ? 1 : 0;
        }
        sorted_s[pos] = t;
        pos_of_s[t] = pos;
    }
    __syncthreads();
    if (t < 64) {
        const int pos = pos_of_s[t];
        segbase_s[t] = (pos < 32) ? 0 : cnt_s[sorted_s[63 - pos]];
    }
    if (t < 32) {
        const int r0 = sorted_s[t], r1 = sorted_s[63 - t];
        pair_rbs[2 * t]     = r0;
        pair_rbs[2 * t + 1] = r1;
        const int c0 = cnt_s[r0];
        const int cT = c0 + cnt_s[r1];
        pair_cnt0[t] = (c0 < PK2 - 2) ? c0 : (PK2 - 2);
        pair_cnt[t]  = (cT < PK2 - 2) ? cT : (PK2 - 2);
    }
    __syncthreads();
    {
        const int pos  = pos_of_s[r];
        const int pair = (pos < 32) ? pos : (63 - pos);
        const int off  = segbase_s[r] + rank;
        if (off < PK2) pk_s[pair * PK2 + off] = (t << 6) | col_idx[t];
    }
    __syncthreads();
    if (t < 64) {   // insertion-sort rb t's segment by ci (pk & 63)
        const int pos  = pos_of_s[t];
        const int pair = (pos < 32) ? pos : (63 - pos);
        int start = pair * PK2 + segbase_s[t];
        int len = cnt_s[t];
        if (segbase_s[t] + len > PK2) len = PK2 - segbase_s[t];
        for (int i = 1; i < len; ++i) {
            const int v = pk_s[start + i];
            int j = i - 1;
            while (j >= 0 && (pk_s[start + j] & 63) > (v & 63)) {
                pk_s[start + j + 1] = pk_s[start + j];
                --j;
            }
            pk_s[start + j + 1] = v;
        }
    }
    __syncthreads();
    for (int i = t; i < 32 * PK2; i += 1024) pair_pk[i] = pk_s[i];
}

// --- main: 8 waves x (32 rows x 64 cols), NT=256, barriered single-buffer --
// LDS 16B-slot swizzle: phys_slot(row,cc)=row*8+(cc^(row&7)); staging lane l
// in chunk ch -> (row=ch*8+l/8, cc=(l&7)^(l/8)); reads xor with m&7.
__global__ __launch_bounds__(512, 4) void bsl_main(
    const unsigned short* __restrict__ xb,   // [4096][4096] bf16
    const unsigned short* __restrict__ blk,  // [1024][64][64] bf16
    const float* __restrict__ bias,
    const int* __restrict__ pair_rbs,
    const int* __restrict__ pair_cnt0,
    const int* __restrict__ pair_cnt,
    const int* __restrict__ pair_pk,
    float* __restrict__ y) {
    __shared__ unsigned short a_lds[NT * 64];   // 32 KB
    __shared__ unsigned short b_lds[64 * 64];   // 8 KB

    const int tid = threadIdx.x;
    const int w = tid >> 6;        // wave 0..7 -> rows [w*32, w*32+32)
    const int l = tid & 63;
    const int m = l & 15;
    const int q = l >> 4;
    const int n0 = blockIdx.x * NT;
    const int p  = blockIdx.y;

    const int srow = l >> 3;
    const int scc  = (l & 7) ^ srow;
    const int xorv = m & 7;

    const int rb0  = pair_rbs[2 * p];
    const int rb1  = pair_rbs[2 * p + 1];
    const int cnt0 = pair_cnt0[p];
    const int cntT = pair_cnt[p];
    const int* plist = pair_pk + p * PK2;

    // staging bases: wave w stages A chunks w*4+i (rows n0+w*32 .. +32)
    const unsigned short* xgw =
        xb + (size_t)(n0 + w * 32 + srow) * IN_DIM + scc * 8;
    const int bg_off = (w * 8 + srow) * 64 + scc * 8;   // B chunk w

    f32x4 acc[2][4];
#pragma unroll
    for (int r = 0; r < 2; ++r)
#pragma unroll
        for (int c = 0; c < 4; ++c) acc[r][c] = (f32x4){0.f, 0.f, 0.f, 0.f};

    auto epilogue = [&](int rb) {
        const int colbase = rb * 64;
#pragma unroll
        for (int c = 0; c < 4; ++c) {
            const float bv = bias[colbase + c * 16 + m];
#pragma unroll
            for (int r = 0; r < 2; ++r) {
                const int rowb = n0 + w * 32 + r * 16 + q * 4;
#pragma unroll
                for (int e = 0; e < 4; ++e)
                    y[(size_t)(rowb + e) * OUT_DIM + colbase + c * 16 + m] =
                        acc[r][c][e] + bv;
            }
        }
    };

    if (cnt0 == 0) epilogue(rb0);   // bias-only first row-block

    int prev_ci = -1;
    for (int kk = 0; kk < cntT; ++kk) {
        const int pk = plist[kk];
        const int k  = pk >> 6;
        const int ci = pk & 63;

        if (ci != prev_ci) {        // wg-uniform; ci-sorted lists make repeats adjacent
#pragma unroll
            for (int i = 0; i < 4; ++i) {
                const int ch = w * 4 + i;
                async_copy16(xgw + (size_t)(i * 8) * IN_DIM + ci * 64,
                             a_lds + ch * 512);
            }
        }
        async_copy16(blk + (size_t)k * 4096 + bg_off, b_lds + w * 512);
        prev_ci = ci;
        __syncthreads();            // drains vmcnt + barrier

#pragma unroll
        for (int s = 0; s < 2; ++s) {
            const int ccp = ((s * 4 + q) ^ xorv) * 8;
            bf16x8 af[2], bf[4];
#pragma unroll
            for (int r = 0; r < 2; ++r)
                af[r] = *(const bf16x8*)(a_lds + (w * 32 + r * 16 + m) * 64 + ccp);
#pragma unroll
            for (int c = 0; c < 4; ++c)
                bf[c] = *(const bf16x8*)(b_lds + (c * 16 + m) * 64 + ccp);
#pragma unroll
            for (int r = 0; r < 2; ++r)
#pragma unroll
                for (int c = 0; c < 4; ++c)
                    acc[r][c] = __builtin_amdgcn_mfma_f32_16x16x32_bf16(
                        af[r], bf[c], acc[r][c], 0, 0, 0);
        }

        if (kk == cnt0 - 1) {       // finish rb0, reset for rb1
            epilogue(rb0);
#pragma unroll
            for (int r = 0; r < 2; ++r)
#pragma unroll
                for (int c = 0; c < 4; ++c)
                    acc[r][c] = (f32x4){0.f, 0.f, 0.f, 0.f};
        }
        __syncthreads();            // protect LDS before next staging
    }
    epilogue(rb1);
}

// ---------------------------------------------------------------------------
extern "C" void kernel_launch(void* const* d_in, const int* in_sizes, int n_in,
                              void* d_out, int out_size, void* d_ws, size_t ws_size,
                              hipStream_t stream) {
    const float* x      = (const float*)d_in[0];
    const float* blocks = (const float*)d_in[1];
    const float* bias   = (const float*)d_in[2];
    const int* row_idx  = (const int*)d_in[3];
    const int* col_idx  = (const int*)d_in[4];
    float* y = (float*)d_out;

    // ws: x_bf16 32MB | blocks_bf16 8MB | meta @40MB:
    //     pair_rbs[64] | pair_cnt0[32] | pair_cnt[32] | pair_pk[32*PK2]
    const size_t base = 41943040u;
    unsigned short* xb = (unsigned short*)d_ws;
    unsigned short* bb = xb + (size_t)4096 * 4096;
    int* pair_rbs  = (int*)((char*)d_ws + base);
    int* pair_cnt0 = pair_rbs + 64;
    int* pair_cnt  = pair_cnt0 + 32;
    int* pair_pk   = pair_cnt + 32;
    if (ws_size < base + (128 + 32 * PK2) * 4) return;

    hipLaunchKernelGGL(bsl_convert, dim3(10240), dim3(256), 0, stream,
                       x, blocks, xb, bb);
    hipLaunchKernelGGL(bsl_build_csr, dim3(1), dim3(1024), 0, stream,
                       row_idx, col_idx, pair_rbs, pair_cnt0, pair_cnt, pair_pk);
    hipLaunchKernelGGL(bsl_main, dim3(16, 32), dim3(512), 0, stream,
                       xb, bb, bias, pair_rbs, pair_cnt0, pair_cnt, pair_pk, y);
}